// Round 6
// baseline (185674.915 us; speedup 1.0000x reference)
//
#include <hip/hip_runtime.h>
#include <hip/hip_cooperative_groups.h>
#include <math.h>

namespace cg = cooperative_groups;

// Problem constants
#define HID   1024
#define G3    3072
#define SENC  4096
#define TDEC  2048
#define NWG   128      // workgroups in recurrence kernel (co-resident via cooperative launch)

// Workspace layout (bytes)
#define GI_OFF    0UL            // 4096*3072*4 = 50331648 (also reused for Smat+Ctx later)
#define S_OFF     0UL            // 2048*4096*4 = 33554432
#define CTX_OFF   33554432UL     // 2048*1024*4 = 8388608
#define X0_OFF    50331648UL     // 4096*1024*4 = 16777216 (reused for dec_emb)
#define DEM_OFF   50331648UL     // 2048*1024*4
#define HL0_OFF   58720256UL     // 2048*1024*4
#define YS0_OFF   67108864UL     // 4096*1024*4 (reused for Hl1 after rec d0)
#define HL1_OFF   67108864UL
#define ENC_OFF   83886080UL     // 4096*1024*4
#define BAR_OFF   100663296UL    // (unused this round; kept for layout stability)
#define H0_OFF    100667392UL    // 4096B zeros
#define WS_NEED   100671488UL

// ---------------- embedding gather ----------------
// shift==0: out[i] = emb[toks[i]];  shift==1: out[0]=emb[start], out[i]=emb[toks[i-1]]
__global__ __launch_bounds__(256) void gather_emb(const float* __restrict__ emb,
                                                  const int* __restrict__ toks,
                                                  float* __restrict__ out,
                                                  int start_tok, int shift)
{
    long i = blockIdx.x;
    int tok = shift ? (i == 0 ? start_tok : toks[i - 1]) : toks[i];
    const float4* src = (const float4*)(emb + (long)tok * HID);
    float4* dst = (float4*)(out + i * (long)HID);
    dst[threadIdx.x] = src[threadIdx.x];   // 256 threads * float4 = 1024 floats
}

// ---------------- f32 GEMM: C[M,N] (+)= A[M,K] * (BT ? B[N,K]^T : B[K,N]) ----------------
// 128x128 tile, BK=16, 256 threads, 8x8 per-thread micro-tile. All dims multiples of 128/16.
template<bool BT, bool ACCUM, bool BIAS>
__global__ __launch_bounds__(256)
void gemm_f32(const float* __restrict__ A, int lda,
              const float* __restrict__ B, int ldb,
              float* __restrict__ C, int ldc,
              int K, const float* __restrict__ bias)
{
    __shared__ float As[16][128];
    __shared__ float Bs[16][128];
    const int tid = threadIdx.x;
    const long m0 = (long)blockIdx.x * 128;
    const long n0 = (long)blockIdx.y * 128;
    const int tm = tid >> 4, tn = tid & 15;
    const int lr = tid >> 2;
    const int lk = (tid & 3) * 4;
    float acc[8][8] = {};

    for (int k0 = 0; k0 < K; k0 += 16) {
        float4 a0 = *(const float4*)(A + (m0 + lr) * (long)lda + k0 + lk);
        float4 a1 = *(const float4*)(A + (m0 + lr + 64) * (long)lda + k0 + lk);
        As[lk + 0][lr] = a0.x; As[lk + 1][lr] = a0.y; As[lk + 2][lr] = a0.z; As[lk + 3][lr] = a0.w;
        As[lk + 0][lr + 64] = a1.x; As[lk + 1][lr + 64] = a1.y; As[lk + 2][lr + 64] = a1.z; As[lk + 3][lr + 64] = a1.w;
        if (BT) {
            float4 b0 = *(const float4*)(B + (n0 + lr) * (long)ldb + k0 + lk);
            float4 b1 = *(const float4*)(B + (n0 + lr + 64) * (long)ldb + k0 + lk);
            Bs[lk + 0][lr] = b0.x; Bs[lk + 1][lr] = b0.y; Bs[lk + 2][lr] = b0.z; Bs[lk + 3][lr] = b0.w;
            Bs[lk + 0][lr + 64] = b1.x; Bs[lk + 1][lr + 64] = b1.y; Bs[lk + 2][lr + 64] = b1.z; Bs[lk + 3][lr + 64] = b1.w;
        } else {
            const int r = tid >> 5;            // 0..7
            const int c4 = (tid & 31) * 4;
            *(float4*)&Bs[r][c4]     = *(const float4*)(B + (long)(k0 + r) * ldb + n0 + c4);
            *(float4*)&Bs[r + 8][c4] = *(const float4*)(B + (long)(k0 + r + 8) * ldb + n0 + c4);
        }
        __syncthreads();
        #pragma unroll
        for (int kk = 0; kk < 16; ++kk) {
            float a[8], b[8];
            *(float4*)&a[0] = *(const float4*)&As[kk][tm * 8];
            *(float4*)&a[4] = *(const float4*)&As[kk][tm * 8 + 4];
            *(float4*)&b[0] = *(const float4*)&Bs[kk][tn * 8];
            *(float4*)&b[4] = *(const float4*)&Bs[kk][tn * 8 + 4];
            #pragma unroll
            for (int i = 0; i < 8; ++i)
                #pragma unroll
                for (int j = 0; j < 8; ++j)
                    acc[i][j] = fmaf(a[i], b[j], acc[i][j]);
        }
        __syncthreads();
    }
    #pragma unroll
    for (int i = 0; i < 8; ++i) {
        float* crow = C + (m0 + tm * 8 + i) * (long)ldc + n0 + tn * 8;
        #pragma unroll
        for (int j = 0; j < 8; ++j) {
            float v = acc[i][j];
            if (BIAS)  v += bias[n0 + tn * 8 + j];
            if (ACCUM) v += crow[j];
            crow[j] = v;
        }
    }
}

// ---------------- persistent GRU recurrence (cooperative launch) ----------------
// 128 wgs x 512 threads. Wave w of wg b owns hidden unit u = b*8+w.
// whh rows u, u+1024, u+2048 live in registers (16 f32 per lane per row).
// Per step: stage h into LDS, 3 dot products + wave reduce, gates, write ys[t][u],
// prefetch gi[t+1], then cg::grid sync (device-scope barrier, co-residency guaranteed).
__global__ __launch_bounds__(512)
void gru_rec(const float* __restrict__ whh, const float* __restrict__ bhh,
             const float* __restrict__ gi, const float* __restrict__ h0,
             float* __restrict__ ys, int T)
{
    cg::grid_group grid = cg::this_grid();
    __shared__ float h_lds[HID];
    const int tid = threadIdx.x;
    const int wave = tid >> 6, lane = tid & 63;
    const int u = blockIdx.x * 8 + wave;
    const int c0 = lane * 16;

    float wr[16], wz[16], wn[16];
    {
        const float* p0 = whh + (long)u * HID + c0;
        const float* p1 = whh + (long)(u + 1024) * HID + c0;
        const float* p2 = whh + (long)(u + 2048) * HID + c0;
        #pragma unroll
        for (int j = 0; j < 16; j += 4) {
            *(float4*)&wr[j] = *(const float4*)(p0 + j);
            *(float4*)&wz[j] = *(const float4*)(p1 + j);
            *(float4*)&wn[j] = *(const float4*)(p2 + j);
        }
    }
    const float br = bhh[u], bz = bhh[u + 1024], bn = bhh[u + 2048];

    // gi for step 0 (prefetched in-register thereafter)
    float ir  = gi[u];
    float iz  = gi[u + 1024];
    float inn = gi[u + 2048];

    const float* hsrc = h0;
    for (int t = 0; t < T; ++t) {
        *(float2*)&h_lds[tid * 2] = *(const float2*)(hsrc + tid * 2);
        __syncthreads();

        float hv[16];
        #pragma unroll
        for (int j = 0; j < 16; j += 4) *(float4*)&hv[j] = *(const float4*)&h_lds[c0 + j];

        float ar = 0.f, az = 0.f, an = 0.f;
        #pragma unroll
        for (int j = 0; j < 16; ++j) {
            ar = fmaf(wr[j], hv[j], ar);
            az = fmaf(wz[j], hv[j], az);
            an = fmaf(wn[j], hv[j], an);
        }
        #pragma unroll
        for (int o = 32; o; o >>= 1) {
            ar += __shfl_xor(ar, o);
            az += __shfl_xor(az, o);
            an += __shfl_xor(an, o);
        }
        if (lane == 0) {
            float r = 1.f / (1.f + expf(-(ir + ar + br)));
            float z = 1.f / (1.f + expf(-(iz + az + bz)));
            float n = tanhf(inn + r * (an + bn));
            ys[(long)t * HID + u] = (1.f - z) * n + z * h_lds[u];
        }
        // prefetch gi for next step (clamped; loads complete during barrier wait)
        {
            const long nbase = (long)(t + 1 < T ? t + 1 : t) * G3 + u;
            ir  = gi[nbase];
            iz  = gi[nbase + 1024];
            inn = gi[nbase + 2048];
        }
        grid.sync();   // device-scope: ys[t] stores visible to all blocks
        hsrc = ys + (long)t * HID;
    }
}

// ---------------- row softmax (2048 rows x 4096 cols, in place) ----------------
__global__ __launch_bounds__(256) void softmax_rows(float* __restrict__ S)
{
    __shared__ float red[8];
    float* p = S + blockIdx.x * 4096L;
    const int t = threadIdx.x;
    const int wave = t >> 6, lane = t & 63;
    float4 v[4];
    float mx = -3.4e38f;
    #pragma unroll
    for (int j = 0; j < 4; ++j) {
        v[j] = *(float4*)(p + (j * 256 + t) * 4);
        mx = fmaxf(mx, fmaxf(fmaxf(v[j].x, v[j].y), fmaxf(v[j].z, v[j].w)));
    }
    #pragma unroll
    for (int o = 32; o; o >>= 1) mx = fmaxf(mx, __shfl_xor(mx, o));
    if (lane == 0) red[wave] = mx;
    __syncthreads();
    mx = fmaxf(fmaxf(red[0], red[1]), fmaxf(red[2], red[3]));
    float sm = 0.f;
    #pragma unroll
    for (int j = 0; j < 4; ++j) {
        v[j].x = expf(v[j].x - mx); v[j].y = expf(v[j].y - mx);
        v[j].z = expf(v[j].z - mx); v[j].w = expf(v[j].w - mx);
        sm += v[j].x + v[j].y + v[j].z + v[j].w;
    }
    #pragma unroll
    for (int o = 32; o; o >>= 1) sm += __shfl_xor(sm, o);
    if (lane == 0) red[4 + wave] = sm;
    __syncthreads();
    sm = red[4] + red[5] + red[6] + red[7];
    const float inv = 1.f / sm;
    #pragma unroll
    for (int j = 0; j < 4; ++j) {
        v[j].x *= inv; v[j].y *= inv; v[j].z *= inv; v[j].w *= inv;
        *(float4*)(p + (j * 256 + t) * 4) = v[j];
    }
}

extern "C" void kernel_launch(void* const* d_in, const int* in_sizes, int n_in,
                              void* d_out, int out_size, void* d_ws, size_t ws_size,
                              hipStream_t stream)
{
    const int*   inputs  = (const int*)d_in[0];
    const int*   targets = (const int*)d_in[1];
    const float* emb     = (const float*)d_in[2];
    const float* ewih0   = (const float*)d_in[3];
    const float* ewhh0   = (const float*)d_in[4];
    const float* ebih0   = (const float*)d_in[5];
    const float* ebhh0   = (const float*)d_in[6];
    const float* ewih1   = (const float*)d_in[7];
    const float* ewhh1   = (const float*)d_in[8];
    const float* ebih1   = (const float*)d_in[9];
    const float* ebhh1   = (const float*)d_in[10];
    const float* dwih0   = (const float*)d_in[11];
    const float* dwhh0   = (const float*)d_in[12];
    const float* dbih0   = (const float*)d_in[13];
    const float* dbhh0   = (const float*)d_in[14];
    const float* dwih1   = (const float*)d_in[15];
    const float* dwhh1   = (const float*)d_in[16];
    const float* dbih1   = (const float*)d_in[17];
    const float* dbhh1   = (const float*)d_in[18];
    const float* proj_w  = (const float*)d_in[19];
    const float* proj_b  = (const float*)d_in[20];
    float* out = (float*)d_out;

    char* ws = (char*)d_ws;
    if (ws_size < WS_NEED) return;   // loud failure instead of corruption

    float* Gi   = (float*)(ws + GI_OFF);
    float* Smat = (float*)(ws + S_OFF);
    float* Ctx  = (float*)(ws + CTX_OFF);
    float* X0   = (float*)(ws + X0_OFF);
    float* Dem  = (float*)(ws + DEM_OFF);
    float* Hl0  = (float*)(ws + HL0_OFF);
    float* ys0  = (float*)(ws + YS0_OFF);
    float* Hl1  = (float*)(ws + HL1_OFF);
    float* Enc  = (float*)(ws + ENC_OFF);
    float* h0z  = (float*)(ws + H0_OFF);

    // zero initial hidden state (+ spare barrier region, kept for layout stability)
    hipMemsetAsync(ws + BAR_OFF, 0, 8192, stream);

    auto launch_rec = [&](const float* whh, const float* bhh, const float* gi,
                          const float* h0p, float* ys, int T) {
        void* args[] = {(void*)&whh, (void*)&bhh, (void*)&gi, (void*)&h0p, (void*)&ys, (void*)&T};
        hipLaunchCooperativeKernel((const void*)gru_rec, dim3(NWG), dim3(512), args, 0, stream);
    };

    // ---- encoder ----
    gather_emb<<<SENC, 256, 0, stream>>>(emb, inputs, X0, 86, 0);
    gemm_f32<true, false, true><<<dim3(32, 24), 256, 0, stream>>>(X0, HID, ewih0, HID, Gi, G3, HID, ebih0);
    launch_rec(ewhh0, ebhh0, Gi, h0z, ys0, SENC);
    gemm_f32<true, false, true><<<dim3(32, 24), 256, 0, stream>>>(ys0, HID, ewih1, HID, Gi, G3, HID, ebih1);
    gather_emb<<<TDEC, 256, 0, stream>>>(emb, targets, Dem, 86, 1);
    launch_rec(ewhh1, ebhh1, Gi, h0z, Enc, SENC);

    // ---- decoder GRU (teacher-forced: input projections batched) ----
    gemm_f32<true, false, true><<<dim3(16, 24), 256, 0, stream>>>(Dem, HID, dwih0, HID, Gi, G3, HID, dbih0);
    launch_rec(dwhh0, dbhh0, Gi, ys0 + 4095L * HID, Hl0, TDEC);
    gemm_f32<true, false, true><<<dim3(16, 24), 256, 0, stream>>>(Hl0, HID, dwih1, HID, Gi, G3, HID, dbih1);
    launch_rec(dwhh1, dbhh1, Gi, Enc + 4095L * HID, Hl1, TDEC);

    // ---- attention + projection (all batched) ----
    gemm_f32<true, false, false><<<dim3(16, 32), 256, 0, stream>>>(Hl1, HID, Enc, HID, Smat, SENC, HID, nullptr);
    softmax_rows<<<TDEC, 256, 0, stream>>>(Smat);
    gemm_f32<false, false, false><<<dim3(16, 8), 256, 0, stream>>>(Smat, SENC, Enc, HID, Ctx, HID, SENC, nullptr);
    gemm_f32<true, false, true><<<dim3(16, 2), 256, 0, stream>>>(Hl1, HID, proj_w, 2 * HID, out, 256, HID, proj_b);
    gemm_f32<true, true, false><<<dim3(16, 2), 256, 0, stream>>>(Ctx, HID, proj_w + HID, 2 * HID, out, 256, HID, nullptr);
}

// Round 11
// 105741.064 us; speedup vs baseline: 1.7559x; 1.7559x over previous
//
#include <hip/hip_runtime.h>
#include <hip/hip_cooperative_groups.h>
#include <math.h>

namespace cg = cooperative_groups;

// Problem constants
#define HID   1024
#define G3    3072
#define SENC  4096
#define TDEC  2048
#define NWG   128      // 64 blocks layer A + 64 blocks layer B (co-resident via cooperative launch)

// Workspace layout (bytes)
#define GI_OFF    0UL            // enc/dec layer-0 gate inputs (50331648 max; reused for Smat later)
#define S_OFF     0UL            // 2048*4096*4 = 33554432
#define CTX_OFF   33554432UL     // 2048*1024*4
#define X0_OFF    50331648UL     // 4096*1024*4 (reused for dec_emb)
#define DEM_OFF   50331648UL
#define HL0_OFF   58720256UL     // 2048*1024*4
#define YS0_OFF   67108864UL     // 4096*1024*4 (enc l0 seq; decoder Hl1 also lives here, rows 0..2047)
#define HL1_OFF   67108864UL
#define ENC_OFF   83886080UL     // 4096*1024*4
#define BAR_OFF   100663296UL    // spare (h0z lives just past it)
#define H0_OFF    100667392UL    // 4096B zeros
#define WS_NEED   100671488UL

__device__ __forceinline__ float wave_red(float v)
{
    #pragma unroll
    for (int o = 32; o; o >>= 1) v += __shfl_xor(v, o);
    return v;
}

// ---------------- embedding gather ----------------
__global__ __launch_bounds__(256) void gather_emb(const float* __restrict__ emb,
                                                  const int* __restrict__ toks,
                                                  float* __restrict__ out,
                                                  int start_tok, int shift)
{
    long i = blockIdx.x;
    int tok = shift ? (i == 0 ? start_tok : toks[i - 1]) : toks[i];
    const float4* src = (const float4*)(emb + (long)tok * HID);
    float4* dst = (float4*)(out + i * (long)HID);
    dst[threadIdx.x] = src[threadIdx.x];
}

// ---------------- f32 GEMM: C[M,N] (+)= A[M,K] * (BT ? B[N,K]^T : B[K,N]) ----------------
template<bool BT, bool ACCUM, bool BIAS>
__global__ __launch_bounds__(256)
void gemm_f32(const float* __restrict__ A, int lda,
              const float* __restrict__ B, int ldb,
              float* __restrict__ C, int ldc,
              int K, const float* __restrict__ bias)
{
    __shared__ float As[16][128];
    __shared__ float Bs[16][128];
    const int tid = threadIdx.x;
    const long m0 = (long)blockIdx.x * 128;
    const long n0 = (long)blockIdx.y * 128;
    const int tm = tid >> 4, tn = tid & 15;
    const int lr = tid >> 2;
    const int lk = (tid & 3) * 4;
    float acc[8][8] = {};

    for (int k0 = 0; k0 < K; k0 += 16) {
        float4 a0 = *(const float4*)(A + (m0 + lr) * (long)lda + k0 + lk);
        float4 a1 = *(const float4*)(A + (m0 + lr + 64) * (long)lda + k0 + lk);
        As[lk + 0][lr] = a0.x; As[lk + 1][lr] = a0.y; As[lk + 2][lr] = a0.z; As[lk + 3][lr] = a0.w;
        As[lk + 0][lr + 64] = a1.x; As[lk + 1][lr + 64] = a1.y; As[lk + 2][lr + 64] = a1.z; As[lk + 3][lr + 64] = a1.w;
        if (BT) {
            float4 b0 = *(const float4*)(B + (n0 + lr) * (long)ldb + k0 + lk);
            float4 b1 = *(const float4*)(B + (n0 + lr + 64) * (long)ldb + k0 + lk);
            Bs[lk + 0][lr] = b0.x; Bs[lk + 1][lr] = b0.y; Bs[lk + 2][lr] = b0.z; Bs[lk + 3][lr] = b0.w;
            Bs[lk + 0][lr + 64] = b1.x; Bs[lk + 1][lr + 64] = b1.y; Bs[lk + 2][lr + 64] = b1.z; Bs[lk + 3][lr + 64] = b1.w;
        } else {
            const int r = tid >> 5;
            const int c4 = (tid & 31) * 4;
            *(float4*)&Bs[r][c4]     = *(const float4*)(B + (long)(k0 + r) * ldb + n0 + c4);
            *(float4*)&Bs[r + 8][c4] = *(const float4*)(B + (long)(k0 + r + 8) * ldb + n0 + c4);
        }
        __syncthreads();
        #pragma unroll
        for (int kk = 0; kk < 16; ++kk) {
            float a[8], b[8];
            *(float4*)&a[0] = *(const float4*)&As[kk][tm * 8];
            *(float4*)&a[4] = *(const float4*)&As[kk][tm * 8 + 4];
            *(float4*)&b[0] = *(const float4*)&Bs[kk][tn * 8];
            *(float4*)&b[4] = *(const float4*)&Bs[kk][tn * 8 + 4];
            #pragma unroll
            for (int i = 0; i < 8; ++i)
                #pragma unroll
                for (int j = 0; j < 8; ++j)
                    acc[i][j] = fmaf(a[i], b[j], acc[i][j]);
        }
        __syncthreads();
    }
    #pragma unroll
    for (int i = 0; i < 8; ++i) {
        float* crow = C + (m0 + tm * 8 + i) * (long)ldc + n0 + tn * 8;
        #pragma unroll
        for (int j = 0; j < 8; ++j) {
            float v = acc[i][j];
            if (BIAS)  v += bias[n0 + tn * 8 + j];
            if (ACCUM) v += crow[j];
            crow[j] = v;
        }
    }
}

// ---------------- fused 2-layer GRU wavefront (cooperative, grid.sync) ----------------
// Blocks 0-63: layer A at step g (gate inputs giA precomputed by GEMM).
// Blocks 64-127: layer B at step s=g-1 (input projection wihB computed in-kernel from ysA[s]).
// Each wave owns 2 adjacent hidden units (u0 even). T+1 grid syncs total.
__global__ __launch_bounds__(512)
void gru2_rec(const float* __restrict__ whhA, const float* __restrict__ bhhA,
              const float* __restrict__ giA,  const float* __restrict__ h0A,
              const float* __restrict__ wihB, const float* __restrict__ bihB,
              const float* __restrict__ whhB, const float* __restrict__ bhhB,
              const float* __restrict__ h0B,
              float* __restrict__ ysA, float* __restrict__ ysB, int T)
{
    cg::grid_group grid = cg::this_grid();
    __shared__ float lds[2048];
    const int tid = threadIdx.x;
    const int wave = tid >> 6, lane = tid & 63;
    const int role = blockIdx.x >> 6;        // 0 = layer A, 1 = layer B
    const int rbid = blockIdx.x & 63;
    const int u0 = (rbid * 8 + wave) * 2;    // even unit index; this wave owns u0, u0+1
    const int c0 = lane * 16;

    if (role == 0) {
        // ---- layer A: recurrent matvec only ----
        float w[3][2][16];
        #pragma unroll
        for (int gt = 0; gt < 3; ++gt)
            #pragma unroll
            for (int k = 0; k < 2; ++k) {
                const float* p = whhA + (long)(u0 + k + gt * 1024) * HID + c0;
                #pragma unroll
                for (int j = 0; j < 16; j += 4) *(float4*)&w[gt][k][j] = *(const float4*)(p + j);
            }
        const float2 bR = *(const float2*)&bhhA[u0];
        const float2 bZ = *(const float2*)&bhhA[u0 + 1024];
        const float2 bN = *(const float2*)&bhhA[u0 + 2048];
        float2 gR = *(const float2*)&giA[u0];
        float2 gZ = *(const float2*)&giA[u0 + 1024];
        float2 gN = *(const float2*)&giA[u0 + 2048];

        for (int g = 0; g <= T; ++g) {
            if (g < T) {
                const float* hsrc = (g == 0) ? h0A : ysA + (long)(g - 1) * HID;
                *(float2*)&lds[tid * 2] = *(const float2*)(hsrc + tid * 2);
                __syncthreads();
                float hv[16];
                #pragma unroll
                for (int j = 0; j < 16; j += 4) *(float4*)&hv[j] = *(const float4*)&lds[c0 + j];
                float a[3][2] = {};
                #pragma unroll
                for (int j = 0; j < 16; ++j)
                    #pragma unroll
                    for (int gt = 0; gt < 3; ++gt) {
                        a[gt][0] = fmaf(w[gt][0][j], hv[j], a[gt][0]);
                        a[gt][1] = fmaf(w[gt][1][j], hv[j], a[gt][1]);
                    }
                #pragma unroll
                for (int gt = 0; gt < 3; ++gt) {
                    a[gt][0] = wave_red(a[gt][0]);
                    a[gt][1] = wave_red(a[gt][1]);
                }
                if (lane == 0) {
                    float r0 = 1.f / (1.f + expf(-(gR.x + a[0][0] + bR.x)));
                    float z0 = 1.f / (1.f + expf(-(gZ.x + a[1][0] + bZ.x)));
                    float n0 = tanhf(gN.x + r0 * (a[2][0] + bN.x));
                    float r1 = 1.f / (1.f + expf(-(gR.y + a[0][1] + bR.y)));
                    float z1 = 1.f / (1.f + expf(-(gZ.y + a[1][1] + bZ.y)));
                    float n1 = tanhf(gN.y + r1 * (a[2][1] + bN.y));
                    float2 hn2;
                    hn2.x = (1.f - z0) * n0 + z0 * lds[u0];
                    hn2.y = (1.f - z1) * n1 + z1 * lds[u0 + 1];
                    *(float2*)&ysA[(long)g * HID + u0] = hn2;
                }
                const long nb = (long)((g + 1 < T) ? g + 1 : g) * G3;
                gR = *(const float2*)&giA[nb + u0];
                gZ = *(const float2*)&giA[nb + u0 + 1024];
                gN = *(const float2*)&giA[nb + u0 + 2048];
            }
            grid.sync();
        }
    } else {
        // ---- layer B: input projection (from ysA) + recurrent matvec ----
        float wi[3][2][16], wh[3][2][16];
        #pragma unroll
        for (int gt = 0; gt < 3; ++gt)
            #pragma unroll
            for (int k = 0; k < 2; ++k) {
                const float* pI = wihB + (long)(u0 + k + gt * 1024) * HID + c0;
                const float* pH = whhB + (long)(u0 + k + gt * 1024) * HID + c0;
                #pragma unroll
                for (int j = 0; j < 16; j += 4) {
                    *(float4*)&wi[gt][k][j] = *(const float4*)(pI + j);
                    *(float4*)&wh[gt][k][j] = *(const float4*)(pH + j);
                }
            }
        const float2 biR = *(const float2*)&bihB[u0];
        const float2 biZ = *(const float2*)&bihB[u0 + 1024];
        const float2 biN = *(const float2*)&bihB[u0 + 2048];
        const float2 bhR = *(const float2*)&bhhB[u0];
        const float2 bhZ = *(const float2*)&bhhB[u0 + 1024];
        const float2 bhN = *(const float2*)&bhhB[u0 + 2048];

        for (int g = 0; g <= T; ++g) {
            const int s = g - 1;
            if (s >= 0) {
                const float* xsrc = ysA + (long)s * HID;
                const float* hsrc = (s == 0) ? h0B : ysB + (long)(s - 1) * HID;
                *(float2*)&lds[tid * 2]        = *(const float2*)(xsrc + tid * 2);
                *(float2*)&lds[1024 + tid * 2] = *(const float2*)(hsrc + tid * 2);
                __syncthreads();
                float xv[16], hv[16];
                #pragma unroll
                for (int j = 0; j < 16; j += 4) {
                    *(float4*)&xv[j] = *(const float4*)&lds[c0 + j];
                    *(float4*)&hv[j] = *(const float4*)&lds[1024 + c0 + j];
                }
                float a_r[2] = {}, a_z[2] = {}, a_ni[2] = {}, a_nh[2] = {};
                #pragma unroll
                for (int j = 0; j < 16; ++j)
                    #pragma unroll
                    for (int k = 0; k < 2; ++k) {
                        a_r[k]  = fmaf(wi[0][k][j], xv[j], a_r[k]);
                        a_r[k]  = fmaf(wh[0][k][j], hv[j], a_r[k]);
                        a_z[k]  = fmaf(wi[1][k][j], xv[j], a_z[k]);
                        a_z[k]  = fmaf(wh[1][k][j], hv[j], a_z[k]);
                        a_ni[k] = fmaf(wi[2][k][j], xv[j], a_ni[k]);
                        a_nh[k] = fmaf(wh[2][k][j], hv[j], a_nh[k]);
                    }
                #pragma unroll
                for (int k = 0; k < 2; ++k) {
                    a_r[k]  = wave_red(a_r[k]);
                    a_z[k]  = wave_red(a_z[k]);
                    a_ni[k] = wave_red(a_ni[k]);
                    a_nh[k] = wave_red(a_nh[k]);
                }
                if (lane == 0) {
                    float r0 = 1.f / (1.f + expf(-(a_r[0] + biR.x + bhR.x)));
                    float z0 = 1.f / (1.f + expf(-(a_z[0] + biZ.x + bhZ.x)));
                    float n0 = tanhf(a_ni[0] + biN.x + r0 * (a_nh[0] + bhN.x));
                    float r1 = 1.f / (1.f + expf(-(a_r[1] + biR.y + bhR.y)));
                    float z1 = 1.f / (1.f + expf(-(a_z[1] + biZ.y + bhZ.y)));
                    float n1 = tanhf(a_ni[1] + biN.y + r1 * (a_nh[1] + bhN.y));
                    float2 hn2;
                    hn2.x = (1.f - z0) * n0 + z0 * lds[1024 + u0];
                    hn2.y = (1.f - z1) * n1 + z1 * lds[1024 + u0 + 1];
                    *(float2*)&ysB[(long)s * HID + u0] = hn2;
                }
            }
            grid.sync();
        }
    }
}

// ---------------- row softmax (2048 rows x 4096 cols, in place) ----------------
__global__ __launch_bounds__(256) void softmax_rows(float* __restrict__ S)
{
    __shared__ float red[8];
    float* p = S + blockIdx.x * 4096L;
    const int t = threadIdx.x;
    const int wave = t >> 6, lane = t & 63;
    float4 v[4];
    float mx = -3.4e38f;
    #pragma unroll
    for (int j = 0; j < 4; ++j) {
        v[j] = *(float4*)(p + (j * 256 + t) * 4);
        mx = fmaxf(mx, fmaxf(fmaxf(v[j].x, v[j].y), fmaxf(v[j].z, v[j].w)));
    }
    #pragma unroll
    for (int o = 32; o; o >>= 1) mx = fmaxf(mx, __shfl_xor(mx, o));
    if (lane == 0) red[wave] = mx;
    __syncthreads();
    mx = fmaxf(fmaxf(red[0], red[1]), fmaxf(red[2], red[3]));
    float sm = 0.f;
    #pragma unroll
    for (int j = 0; j < 4; ++j) {
        v[j].x = expf(v[j].x - mx); v[j].y = expf(v[j].y - mx);
        v[j].z = expf(v[j].z - mx); v[j].w = expf(v[j].w - mx);
        sm += v[j].x + v[j].y + v[j].z + v[j].w;
    }
    #pragma unroll
    for (int o = 32; o; o >>= 1) sm += __shfl_xor(sm, o);
    if (lane == 0) red[4 + wave] = sm;
    __syncthreads();
    sm = red[4] + red[5] + red[6] + red[7];
    const float inv = 1.f / sm;
    #pragma unroll
    for (int j = 0; j < 4; ++j) {
        v[j].x *= inv; v[j].y *= inv; v[j].z *= inv; v[j].w *= inv;
        *(float4*)(p + (j * 256 + t) * 4) = v[j];
    }
}

extern "C" void kernel_launch(void* const* d_in, const int* in_sizes, int n_in,
                              void* d_out, int out_size, void* d_ws, size_t ws_size,
                              hipStream_t stream)
{
    const int*   inputs  = (const int*)d_in[0];
    const int*   targets = (const int*)d_in[1];
    const float* emb     = (const float*)d_in[2];
    const float* ewih0   = (const float*)d_in[3];
    const float* ewhh0   = (const float*)d_in[4];
    const float* ebih0   = (const float*)d_in[5];
    const float* ebhh0   = (const float*)d_in[6];
    const float* ewih1   = (const float*)d_in[7];
    const float* ewhh1   = (const float*)d_in[8];
    const float* ebih1   = (const float*)d_in[9];
    const float* ebhh1   = (const float*)d_in[10];
    const float* dwih0   = (const float*)d_in[11];
    const float* dwhh0   = (const float*)d_in[12];
    const float* dbih0   = (const float*)d_in[13];
    const float* dbhh0   = (const float*)d_in[14];
    const float* dwih1   = (const float*)d_in[15];
    const float* dwhh1   = (const float*)d_in[16];
    const float* dbih1   = (const float*)d_in[17];
    const float* dbhh1   = (const float*)d_in[18];
    const float* proj_w  = (const float*)d_in[19];
    const float* proj_b  = (const float*)d_in[20];
    float* out = (float*)d_out;

    char* ws = (char*)d_ws;
    if (ws_size < WS_NEED) return;

    float* Gi   = (float*)(ws + GI_OFF);
    float* Smat = (float*)(ws + S_OFF);
    float* Ctx  = (float*)(ws + CTX_OFF);
    float* X0   = (float*)(ws + X0_OFF);
    float* Dem  = (float*)(ws + DEM_OFF);
    float* Hl0  = (float*)(ws + HL0_OFF);
    float* ys0  = (float*)(ws + YS0_OFF);
    float* Hl1  = (float*)(ws + HL1_OFF);
    float* Enc  = (float*)(ws + ENC_OFF);
    float* h0z  = (float*)(ws + H0_OFF);

    // zero initial hidden state (+ spare region)
    hipMemsetAsync(ws + BAR_OFF, 0, 8192, stream);

    auto launch_rec2 = [&](const float* whhA, const float* bhhA, const float* giA, const float* h0A,
                           const float* wihB, const float* bihB, const float* whhB, const float* bhhB,
                           const float* h0B, float* ysA, float* ysB, int T) {
        void* args[] = {(void*)&whhA, (void*)&bhhA, (void*)&giA, (void*)&h0A,
                        (void*)&wihB, (void*)&bihB, (void*)&whhB, (void*)&bhhB,
                        (void*)&h0B, (void*)&ysA, (void*)&ysB, (void*)&T};
        hipLaunchCooperativeKernel((const void*)gru2_rec, dim3(NWG), dim3(512), args, 0, stream);
    };

    // ---- encoder: gather + l0 gate-input GEMM, then fused l0+l1 wavefront ----
    gather_emb<<<SENC, 256, 0, stream>>>(emb, inputs, X0, 86, 0);
    gemm_f32<true, false, true><<<dim3(32, 24), 256, 0, stream>>>(X0, HID, ewih0, HID, Gi, G3, HID, ebih0);
    gather_emb<<<TDEC, 256, 0, stream>>>(emb, targets, Dem, 86, 1);
    launch_rec2(ewhh0, ebhh0, Gi, h0z,
                ewih1, ebih1, ewhh1, ebhh1, h0z,
                ys0, Enc, SENC);

    // ---- decoder: l0 gate-input GEMM, then fused l0+l1 wavefront ----
    gemm_f32<true, false, true><<<dim3(16, 24), 256, 0, stream>>>(Dem, HID, dwih0, HID, Gi, G3, HID, dbih0);
    launch_rec2(dwhh0, dbhh0, Gi, ys0 + 4095L * HID,
                dwih1, dbih1, dwhh1, dbhh1, Enc + 4095L * HID,
                Hl0, Hl1, TDEC);

    // ---- attention + projection (all batched) ----
    gemm_f32<true, false, false><<<dim3(16, 32), 256, 0, stream>>>(Hl1, HID, Enc, HID, Smat, SENC, HID, nullptr);
    softmax_rows<<<TDEC, 256, 0, stream>>>(Smat);
    gemm_f32<false, false, false><<<dim3(16, 8), 256, 0, stream>>>(Smat, SENC, Enc, HID, Ctx, HID, SENC, nullptr);
    gemm_f32<true, false, true><<<dim3(16, 2), 256, 0, stream>>>(Hl1, HID, proj_w, 2 * HID, out, 256, HID, proj_b);
    gemm_f32<true, true, false><<<dim3(16, 2), 256, 0, stream>>>(Ctx, HID, proj_w + HID, 2 * HID, out, 256, HID, nullptr);
}

// Round 12
// 48507.123 us; speedup vs baseline: 3.8278x; 2.1799x over previous
//
#include <hip/hip_runtime.h>
#include <math.h>

// Problem constants
#define HID   1024
#define G3    3072
#define SENC  4096
#define TDEC  2048
#define NWG   128      // 64 blocks layer A + 64 blocks layer B (co-resident via cooperative launch)

// Workspace layout (bytes)
#define GI_OFF    0UL            // enc/dec layer-0 gate inputs (reused for Smat later)
#define S_OFF     0UL            // 2048*4096*4 = 33554432
#define CTX_OFF   33554432UL     // 2048*1024*4
#define X0_OFF    50331648UL     // 4096*1024*4 (reused for dec_emb)
#define DEM_OFF   50331648UL
#define HL0_OFF   58720256UL     // 2048*1024*4
#define YS0_OFF   67108864UL     // 4096*1024*4 (enc l0 seq; decoder Hl1 also lives here)
#define HL1_OFF   67108864UL
#define ENC_OFF   83886080UL     // 4096*1024*4
#define BAR_OFF   100663296UL    // barrier counters (monotone, zeroed each launch)
#define H0_OFF    100667392UL    // 4096B zeros
#define WS_NEED   100671488UL

__device__ __forceinline__ float wave_red(float v)
{
    #pragma unroll
    for (int o = 32; o; o >>= 1) v += __shfl_xor(v, o);
    return v;
}

// MALL-coherent (agent-scope, sc1) 8-byte accesses: write-through / cache-bypassing.
__device__ __forceinline__ unsigned long long ld_mall(const void* p)
{
    return __hip_atomic_load((const unsigned long long*)p, __ATOMIC_RELAXED, __HIP_MEMORY_SCOPE_AGENT);
}
__device__ __forceinline__ void st_mall(void* p, unsigned long long v)
{
    __hip_atomic_store((unsigned long long*)p, v, __ATOMIC_RELAXED, __HIP_MEMORY_SCOPE_AGENT);
}

// ---------------- embedding gather ----------------
__global__ __launch_bounds__(256) void gather_emb(const float* __restrict__ emb,
                                                  const int* __restrict__ toks,
                                                  float* __restrict__ out,
                                                  int start_tok, int shift)
{
    long i = blockIdx.x;
    int tok = shift ? (i == 0 ? start_tok : toks[i - 1]) : toks[i];
    const float4* src = (const float4*)(emb + (long)tok * HID);
    float4* dst = (float4*)(out + i * (long)HID);
    dst[threadIdx.x] = src[threadIdx.x];
}

// ---------------- f32 GEMM: C[M,N] (+)= A[M,K] * (BT ? B[N,K]^T : B[K,N]) ----------------
template<bool BT, bool ACCUM, bool BIAS>
__global__ __launch_bounds__(256)
void gemm_f32(const float* __restrict__ A, int lda,
              const float* __restrict__ B, int ldb,
              float* __restrict__ C, int ldc,
              int K, const float* __restrict__ bias)
{
    __shared__ float As[16][128];
    __shared__ float Bs[16][128];
    const int tid = threadIdx.x;
    const long m0 = (long)blockIdx.x * 128;
    const long n0 = (long)blockIdx.y * 128;
    const int tm = tid >> 4, tn = tid & 15;
    const int lr = tid >> 2;
    const int lk = (tid & 3) * 4;
    float acc[8][8] = {};

    for (int k0 = 0; k0 < K; k0 += 16) {
        float4 a0 = *(const float4*)(A + (m0 + lr) * (long)lda + k0 + lk);
        float4 a1 = *(const float4*)(A + (m0 + lr + 64) * (long)lda + k0 + lk);
        As[lk + 0][lr] = a0.x; As[lk + 1][lr] = a0.y; As[lk + 2][lr] = a0.z; As[lk + 3][lr] = a0.w;
        As[lk + 0][lr + 64] = a1.x; As[lk + 1][lr + 64] = a1.y; As[lk + 2][lr + 64] = a1.z; As[lk + 3][lr + 64] = a1.w;
        if (BT) {
            float4 b0 = *(const float4*)(B + (n0 + lr) * (long)ldb + k0 + lk);
            float4 b1 = *(const float4*)(B + (n0 + lr + 64) * (long)ldb + k0 + lk);
            Bs[lk + 0][lr] = b0.x; Bs[lk + 1][lr] = b0.y; Bs[lk + 2][lr] = b0.z; Bs[lk + 3][lr] = b0.w;
            Bs[lk + 0][lr + 64] = b1.x; Bs[lk + 1][lr + 64] = b1.y; Bs[lk + 2][lr + 64] = b1.z; Bs[lk + 3][lr + 64] = b1.w;
        } else {
            const int r = tid >> 5;
            const int c4 = (tid & 31) * 4;
            *(float4*)&Bs[r][c4]     = *(const float4*)(B + (long)(k0 + r) * ldb + n0 + c4);
            *(float4*)&Bs[r + 8][c4] = *(const float4*)(B + (long)(k0 + r + 8) * ldb + n0 + c4);
        }
        __syncthreads();
        #pragma unroll
        for (int kk = 0; kk < 16; ++kk) {
            float a[8], b[8];
            *(float4*)&a[0] = *(const float4*)&As[kk][tm * 8];
            *(float4*)&a[4] = *(const float4*)&As[kk][tm * 8 + 4];
            *(float4*)&b[0] = *(const float4*)&Bs[kk][tn * 8];
            *(float4*)&b[4] = *(const float4*)&Bs[kk][tn * 8 + 4];
            #pragma unroll
            for (int i = 0; i < 8; ++i)
                #pragma unroll
                for (int j = 0; j < 8; ++j)
                    acc[i][j] = fmaf(a[i], b[j], acc[i][j]);
        }
        __syncthreads();
    }
    #pragma unroll
    for (int i = 0; i < 8; ++i) {
        float* crow = C + (m0 + tm * 8 + i) * (long)ldc + n0 + tn * 8;
        #pragma unroll
        for (int j = 0; j < 8; ++j) {
            float v = acc[i][j];
            if (BIAS)  v += bias[n0 + tn * 8 + j];
            if (ACCUM) v += crow[j];
            crow[j] = v;
        }
    }
}

// ---------------- fused 2-layer GRU wavefront (cooperative launch, monotone MALL barrier) ----------------
// Blocks 0-63: layer A at step g. Blocks 64-127: layer B at step g-1 (consumes ysA[g-1]).
// ys published via agent-scope (sc1) write-through atomic stores; h/x staged via agent-scope
// atomic loads (MALL = single coherence point; no fences). Barrier: monotone counter —
// fetch_add(cnt,1) then spin until cnt >= NWG*(g+1). No resets => no lost-arrival/ABA race.
// __syncthreads() before arrival drains vmcnt (sc1 stores complete at MALL first).
// Spin guard (~1s) flips a sticky 'dead' flag; arrivals always continue => no hang possible.
__global__ __launch_bounds__(512)
void gru2_rec(const float* __restrict__ whhA, const float* __restrict__ bhhA,
              const float* __restrict__ giA,  const float* __restrict__ h0A,
              const float* __restrict__ wihB, const float* __restrict__ bihB,
              const float* __restrict__ whhB, const float* __restrict__ bhhB,
              const float* __restrict__ h0B,
              float* __restrict__ ysA, float* __restrict__ ysB, int T,
              unsigned* __restrict__ cnt)
{
    __shared__ float lds[2048];
    const int tid = threadIdx.x;
    const int wave = tid >> 6, lane = tid & 63;
    const int role = blockIdx.x >> 6;        // 0 = layer A, 1 = layer B
    const int rbid = blockIdx.x & 63;
    const int u0 = (rbid * 8 + wave) * 2;    // even unit index; this wave owns u0, u0+1
    const int c0 = lane * 16;
    bool dead = false;

    union { unsigned long long q; float f[2]; float2 v; } cv;

    if (role == 0) {
        // ---- layer A: recurrent matvec only ----
        float w[3][2][16];
        #pragma unroll
        for (int gt = 0; gt < 3; ++gt)
            #pragma unroll
            for (int k = 0; k < 2; ++k) {
                const float* p = whhA + (long)(u0 + k + gt * 1024) * HID + c0;
                #pragma unroll
                for (int j = 0; j < 16; j += 4) *(float4*)&w[gt][k][j] = *(const float4*)(p + j);
            }
        const float2 bR = *(const float2*)&bhhA[u0];
        const float2 bZ = *(const float2*)&bhhA[u0 + 1024];
        const float2 bN = *(const float2*)&bhhA[u0 + 2048];
        float2 gR = *(const float2*)&giA[u0];
        float2 gZ = *(const float2*)&giA[u0 + 1024];
        float2 gN = *(const float2*)&giA[u0 + 2048];

        for (int g = 0; g <= T; ++g) {
            if (g < T) {
                const float* hsrc = (g == 0) ? h0A : ysA + (long)(g - 1) * HID;
                cv.q = ld_mall((const unsigned long long*)hsrc + tid);
                lds[tid * 2] = cv.f[0]; lds[tid * 2 + 1] = cv.f[1];
                __syncthreads();
                float hv[16];
                #pragma unroll
                for (int j = 0; j < 16; j += 4) *(float4*)&hv[j] = *(const float4*)&lds[c0 + j];
                float a[3][2] = {};
                #pragma unroll
                for (int j = 0; j < 16; ++j)
                    #pragma unroll
                    for (int gt = 0; gt < 3; ++gt) {
                        a[gt][0] = fmaf(w[gt][0][j], hv[j], a[gt][0]);
                        a[gt][1] = fmaf(w[gt][1][j], hv[j], a[gt][1]);
                    }
                #pragma unroll
                for (int gt = 0; gt < 3; ++gt) {
                    a[gt][0] = wave_red(a[gt][0]);
                    a[gt][1] = wave_red(a[gt][1]);
                }
                if (lane == 0) {
                    float r0 = 1.f / (1.f + expf(-(gR.x + a[0][0] + bR.x)));
                    float z0 = 1.f / (1.f + expf(-(gZ.x + a[1][0] + bZ.x)));
                    float n0 = tanhf(gN.x + r0 * (a[2][0] + bN.x));
                    float r1 = 1.f / (1.f + expf(-(gR.y + a[0][1] + bR.y)));
                    float z1 = 1.f / (1.f + expf(-(gZ.y + a[1][1] + bZ.y)));
                    float n1 = tanhf(gN.y + r1 * (a[2][1] + bN.y));
                    union { unsigned long long q; float2 v; } outv;
                    outv.v.x = (1.f - z0) * n0 + z0 * lds[u0];
                    outv.v.y = (1.f - z1) * n1 + z1 * lds[u0 + 1];
                    st_mall(&ysA[(long)g * HID + u0], outv.q);
                }
                const long nb = (long)((g + 1 < T) ? g + 1 : g) * G3;
                gR = *(const float2*)&giA[nb + u0];
                gZ = *(const float2*)&giA[nb + u0 + 1024];
                gN = *(const float2*)&giA[nb + u0 + 2048];
            }
            __syncthreads();   // drains vmcnt: sc1 ys stores complete at MALL before arrival
            if (tid == 0) {
                __hip_atomic_fetch_add(cnt, 1u, __ATOMIC_RELAXED, __HIP_MEMORY_SCOPE_AGENT);
                if (!dead) {
                    const unsigned target = (unsigned)(g + 1) * NWG;
                    int guard = 0;
                    while (__hip_atomic_load(cnt, __ATOMIC_RELAXED, __HIP_MEMORY_SCOPE_AGENT) < target) {
                        __builtin_amdgcn_s_sleep(1);
                        if (++guard > (1 << 22)) { dead = true; break; }
                    }
                }
            }
            __syncthreads();
        }
    } else {
        // ---- layer B: input projection (from ysA) + recurrent matvec ----
        float wi[3][2][16], wh[3][2][16];
        #pragma unroll
        for (int gt = 0; gt < 3; ++gt)
            #pragma unroll
            for (int k = 0; k < 2; ++k) {
                const float* pI = wihB + (long)(u0 + k + gt * 1024) * HID + c0;
                const float* pH = whhB + (long)(u0 + k + gt * 1024) * HID + c0;
                #pragma unroll
                for (int j = 0; j < 16; j += 4) {
                    *(float4*)&wi[gt][k][j] = *(const float4*)(pI + j);
                    *(float4*)&wh[gt][k][j] = *(const float4*)(pH + j);
                }
            }
        const float2 biR = *(const float2*)&bihB[u0];
        const float2 biZ = *(const float2*)&bihB[u0 + 1024];
        const float2 biN = *(const float2*)&bihB[u0 + 2048];
        const float2 bhR = *(const float2*)&bhhB[u0];
        const float2 bhZ = *(const float2*)&bhhB[u0 + 1024];
        const float2 bhN = *(const float2*)&bhhB[u0 + 2048];

        for (int g = 0; g <= T; ++g) {
            const int s = g - 1;
            if (s >= 0) {
                const float* xsrc = ysA + (long)s * HID;
                const float* hsrc = (s == 0) ? h0B : ysB + (long)(s - 1) * HID;
                cv.q = ld_mall((const unsigned long long*)xsrc + tid);
                lds[tid * 2] = cv.f[0]; lds[tid * 2 + 1] = cv.f[1];
                cv.q = ld_mall((const unsigned long long*)hsrc + tid);
                lds[1024 + tid * 2] = cv.f[0]; lds[1024 + tid * 2 + 1] = cv.f[1];
                __syncthreads();
                float xv[16], hv[16];
                #pragma unroll
                for (int j = 0; j < 16; j += 4) {
                    *(float4*)&xv[j] = *(const float4*)&lds[c0 + j];
                    *(float4*)&hv[j] = *(const float4*)&lds[1024 + c0 + j];
                }
                float a_r[2] = {}, a_z[2] = {}, a_ni[2] = {}, a_nh[2] = {};
                #pragma unroll
                for (int j = 0; j < 16; ++j)
                    #pragma unroll
                    for (int k = 0; k < 2; ++k) {
                        a_r[k]  = fmaf(wi[0][k][j], xv[j], a_r[k]);
                        a_r[k]  = fmaf(wh[0][k][j], hv[j], a_r[k]);
                        a_z[k]  = fmaf(wi[1][k][j], xv[j], a_z[k]);
                        a_z[k]  = fmaf(wh[1][k][j], hv[j], a_z[k]);
                        a_ni[k] = fmaf(wi[2][k][j], xv[j], a_ni[k]);
                        a_nh[k] = fmaf(wh[2][k][j], hv[j], a_nh[k]);
                    }
                #pragma unroll
                for (int k = 0; k < 2; ++k) {
                    a_r[k]  = wave_red(a_r[k]);
                    a_z[k]  = wave_red(a_z[k]);
                    a_ni[k] = wave_red(a_ni[k]);
                    a_nh[k] = wave_red(a_nh[k]);
                }
                if (lane == 0) {
                    float r0 = 1.f / (1.f + expf(-(a_r[0] + biR.x + bhR.x)));
                    float z0 = 1.f / (1.f + expf(-(a_z[0] + biZ.x + bhZ.x)));
                    float n0 = tanhf(a_ni[0] + biN.x + r0 * (a_nh[0] + bhN.x));
                    float r1 = 1.f / (1.f + expf(-(a_r[1] + biR.y + bhR.y)));
                    float z1 = 1.f / (1.f + expf(-(a_z[1] + biZ.y + bhZ.y)));
                    float n1 = tanhf(a_ni[1] + biN.y + r1 * (a_nh[1] + bhN.y));
                    union { unsigned long long q; float2 v; } outv;
                    outv.v.x = (1.f - z0) * n0 + z0 * lds[1024 + u0];
                    outv.v.y = (1.f - z1) * n1 + z1 * lds[1024 + u0 + 1];
                    st_mall(&ysB[(long)s * HID + u0], outv.q);
                }
            }
            __syncthreads();   // drains vmcnt before arrival
            if (tid == 0) {
                __hip_atomic_fetch_add(cnt, 1u, __ATOMIC_RELAXED, __HIP_MEMORY_SCOPE_AGENT);
                if (!dead) {
                    const unsigned target = (unsigned)(g + 1) * NWG;
                    int guard = 0;
                    while (__hip_atomic_load(cnt, __ATOMIC_RELAXED, __HIP_MEMORY_SCOPE_AGENT) < target) {
                        __builtin_amdgcn_s_sleep(1);
                        if (++guard > (1 << 22)) { dead = true; break; }
                    }
                }
            }
            __syncthreads();
        }
    }
}

// ---------------- row softmax (2048 rows x 4096 cols, in place) ----------------
__global__ __launch_bounds__(256) void softmax_rows(float* __restrict__ S)
{
    __shared__ float red[8];
    float* p = S + blockIdx.x * 4096L;
    const int t = threadIdx.x;
    const int wave = t >> 6, lane = t & 63;
    float4 v[4];
    float mx = -3.4e38f;
    #pragma unroll
    for (int j = 0; j < 4; ++j) {
        v[j] = *(float4*)(p + (j * 256 + t) * 4);
        mx = fmaxf(mx, fmaxf(fmaxf(v[j].x, v[j].y), fmaxf(v[j].z, v[j].w)));
    }
    #pragma unroll
    for (int o = 32; o; o >>= 1) mx = fmaxf(mx, __shfl_xor(mx, o));
    if (lane == 0) red[wave] = mx;
    __syncthreads();
    mx = fmaxf(fmaxf(red[0], red[1]), fmaxf(red[2], red[3]));
    float sm = 0.f;
    #pragma unroll
    for (int j = 0; j < 4; ++j) {
        v[j].x = expf(v[j].x - mx); v[j].y = expf(v[j].y - mx);
        v[j].z = expf(v[j].z - mx); v[j].w = expf(v[j].w - mx);
        sm += v[j].x + v[j].y + v[j].z + v[j].w;
    }
    #pragma unroll
    for (int o = 32; o; o >>= 1) sm += __shfl_xor(sm, o);
    if (lane == 0) red[4 + wave] = sm;
    __syncthreads();
    sm = red[4] + red[5] + red[6] + red[7];
    const float inv = 1.f / sm;
    #pragma unroll
    for (int j = 0; j < 4; ++j) {
        v[j].x *= inv; v[j].y *= inv; v[j].z *= inv; v[j].w *= inv;
        *(float4*)(p + (j * 256 + t) * 4) = v[j];
    }
}

extern "C" void kernel_launch(void* const* d_in, const int* in_sizes, int n_in,
                              void* d_out, int out_size, void* d_ws, size_t ws_size,
                              hipStream_t stream)
{
    const int*   inputs  = (const int*)d_in[0];
    const int*   targets = (const int*)d_in[1];
    const float* emb     = (const float*)d_in[2];
    const float* ewih0   = (const float*)d_in[3];
    const float* ewhh0   = (const float*)d_in[4];
    const float* ebih0   = (const float*)d_in[5];
    const float* ebhh0   = (const float*)d_in[6];
    const float* ewih1   = (const float*)d_in[7];
    const float* ewhh1   = (const float*)d_in[8];
    const float* ebih1   = (const float*)d_in[9];
    const float* ebhh1   = (const float*)d_in[10];
    const float* dwih0   = (const float*)d_in[11];
    const float* dwhh0   = (const float*)d_in[12];
    const float* dbih0   = (const float*)d_in[13];
    const float* dbhh0   = (const float*)d_in[14];
    const float* dwih1   = (const float*)d_in[15];
    const float* dwhh1   = (const float*)d_in[16];
    const float* dbih1   = (const float*)d_in[17];
    const float* dbhh1   = (const float*)d_in[18];
    const float* proj_w  = (const float*)d_in[19];
    const float* proj_b  = (const float*)d_in[20];
    float* out = (float*)d_out;

    char* ws = (char*)d_ws;
    if (ws_size < WS_NEED) return;

    float* Gi   = (float*)(ws + GI_OFF);
    float* Smat = (float*)(ws + S_OFF);
    float* Ctx  = (float*)(ws + CTX_OFF);
    float* X0   = (float*)(ws + X0_OFF);
    float* Dem  = (float*)(ws + DEM_OFF);
    float* Hl0  = (float*)(ws + HL0_OFF);
    float* ys0  = (float*)(ws + YS0_OFF);
    float* Hl1  = (float*)(ws + HL1_OFF);
    float* Enc  = (float*)(ws + ENC_OFF);
    unsigned* bar = (unsigned*)(ws + BAR_OFF);
    float* h0z  = (float*)(ws + H0_OFF);

    // zero barrier counters + initial hidden state (re-runs on every graph replay)
    hipMemsetAsync(ws + BAR_OFF, 0, 8192, stream);

    auto launch_rec2 = [&](const float* whhA, const float* bhhA, const float* giA, const float* h0A,
                           const float* wihB, const float* bihB, const float* whhB, const float* bhhB,
                           const float* h0B, float* ysA, float* ysB, int T, unsigned* cntp) {
        void* args[] = {(void*)&whhA, (void*)&bhhA, (void*)&giA, (void*)&h0A,
                        (void*)&wihB, (void*)&bihB, (void*)&whhB, (void*)&bhhB,
                        (void*)&h0B, (void*)&ysA, (void*)&ysB, (void*)&T, (void*)&cntp};
        hipLaunchCooperativeKernel((const void*)gru2_rec, dim3(NWG), dim3(512), args, 0, stream);
    };

    // ---- encoder: gather + l0 gate-input GEMM, then fused l0+l1 wavefront ----
    gather_emb<<<SENC, 256, 0, stream>>>(emb, inputs, X0, 86, 0);
    gemm_f32<true, false, true><<<dim3(32, 24), 256, 0, stream>>>(X0, HID, ewih0, HID, Gi, G3, HID, ebih0);
    gather_emb<<<TDEC, 256, 0, stream>>>(emb, targets, Dem, 86, 1);
    launch_rec2(ewhh0, ebhh0, Gi, h0z,
                ewih1, ebih1, ewhh1, ebhh1, h0z,
                ys0, Enc, SENC, bar + 0);

    // ---- decoder: l0 gate-input GEMM, then fused l0+l1 wavefront ----
    gemm_f32<true, false, true><<<dim3(16, 24), 256, 0, stream>>>(Dem, HID, dwih0, HID, Gi, G3, HID, dbih0);
    launch_rec2(dwhh0, dbhh0, Gi, ys0 + 4095L * HID,
                dwih1, dbih1, dwhh1, dbhh1, Enc + 4095L * HID,
                Hl0, Hl1, TDEC, bar + 64);

    // ---- attention + projection (all batched) ----
    gemm_f32<true, false, false><<<dim3(16, 32), 256, 0, stream>>>(Hl1, HID, Enc, HID, Smat, SENC, HID, nullptr);
    softmax_rows<<<TDEC, 256, 0, stream>>>(Smat);
    gemm_f32<false, false, false><<<dim3(16, 8), 256, 0, stream>>>(Smat, SENC, Enc, HID, Ctx, HID, SENC, nullptr);
    gemm_f32<true, false, true><<<dim3(16, 2), 256, 0, stream>>>(Hl1, HID, proj_w, 2 * HID, out, 256, HID, proj_b);
    gemm_f32<true, true, false><<<dim3(16, 2), 256, 0, stream>>>(Ctx, HID, proj_w + HID, 2 * HID, out, 256, HID, nullptr);
}

// Round 13
// 37584.183 us; speedup vs baseline: 4.9402x; 1.2906x over previous
//
#include <hip/hip_runtime.h>
#include <math.h>

// Problem constants
#define HID   1024
#define G3    3072
#define SENC  4096
#define TDEC  2048
#define NWG   128      // 64 blocks layer A + 64 blocks layer B (co-resident via cooperative launch)

// Workspace layout (bytes)
#define GI_OFF    0UL            // enc/dec layer-0 gate inputs (reused for Smat later)
#define S_OFF     0UL            // 2048*4096*4 = 33554432
#define CTX_OFF   33554432UL     // 2048*1024*4
#define X0_OFF    50331648UL     // 4096*1024*4 (reused for dec_emb)
#define DEM_OFF   50331648UL
#define HL0_OFF   58720256UL     // 2048*1024*4
#define YS0_OFF   67108864UL     // 4096*1024*4 (enc l0 seq; decoder Hl1 also lives here)
#define HL1_OFF   67108864UL
#define ENC_OFF   83886080UL     // 4096*1024*4
#define BAR_OFF   100663296UL    // barrier counters (monotone tree, zeroed each launch)
#define H0_OFF    100667392UL    // 4096B zeros
#define WS_NEED   100671488UL

__device__ __forceinline__ float wave_red(float v)
{
    #pragma unroll
    for (int o = 32; o; o >>= 1) v += __shfl_xor(v, o);
    return v;
}

// MALL-coherent (agent-scope, sc1) 8-byte accesses: write-through / cache-bypassing.
__device__ __forceinline__ unsigned long long ld_mall(const void* p)
{
    return __hip_atomic_load((const unsigned long long*)p, __ATOMIC_RELAXED, __HIP_MEMORY_SCOPE_AGENT);
}
__device__ __forceinline__ void st_mall(void* p, unsigned long long v)
{
    __hip_atomic_store((unsigned long long*)p, v, __ATOMIC_RELAXED, __HIP_MEMORY_SCOPE_AGENT);
}

// Two-level monotone tree barrier (no resets => no lost-arrival/ABA race class).
// bar layout (words): group counters at 0,16,...,112 (8 groups x 16 blocks, 64B apart); root at 128.
// Arrival: fetch_add(group). The arrival whose old value == 16g+15 is the group leader for
// generation g and bumps root. Everyone polls root >= 8(g+1). Serialized RMW chain: 16+8=24
// (vs 128 on one line). Sticky dead-flag guard => wrong answer, never a hang.
__device__ __forceinline__ void tree_barrier(unsigned* __restrict__ bar, int g, int bid, bool& dead)
{
    unsigned* grp  = bar + (bid >> 4) * 16;
    unsigned* root = bar + 128;
    unsigned old = __hip_atomic_fetch_add(grp, 1u, __ATOMIC_RELAXED, __HIP_MEMORY_SCOPE_AGENT);
    if (old == (unsigned)(16 * g + 15))
        __hip_atomic_fetch_add(root, 1u, __ATOMIC_RELAXED, __HIP_MEMORY_SCOPE_AGENT);
    if (!dead) {
        const unsigned target = 8u * (unsigned)(g + 1);
        int guard = 0;
        while (__hip_atomic_load(root, __ATOMIC_RELAXED, __HIP_MEMORY_SCOPE_AGENT) < target) {
            __builtin_amdgcn_s_sleep(1);
            if (++guard > (1 << 22)) { dead = true; break; }
        }
    }
}

// ---------------- embedding gather ----------------
__global__ __launch_bounds__(256) void gather_emb(const float* __restrict__ emb,
                                                  const int* __restrict__ toks,
                                                  float* __restrict__ out,
                                                  int start_tok, int shift)
{
    long i = blockIdx.x;
    int tok = shift ? (i == 0 ? start_tok : toks[i - 1]) : toks[i];
    const float4* src = (const float4*)(emb + (long)tok * HID);
    float4* dst = (float4*)(out + i * (long)HID);
    dst[threadIdx.x] = src[threadIdx.x];
}

// ---------------- f32 GEMM: C[M,N] (+)= A[M,K] * (BT ? B[N,K]^T : B[K,N]) ----------------
template<bool BT, bool ACCUM, bool BIAS>
__global__ __launch_bounds__(256)
void gemm_f32(const float* __restrict__ A, int lda,
              const float* __restrict__ B, int ldb,
              float* __restrict__ C, int ldc,
              int K, const float* __restrict__ bias)
{
    __shared__ float As[16][128];
    __shared__ float Bs[16][128];
    const int tid = threadIdx.x;
    const long m0 = (long)blockIdx.x * 128;
    const long n0 = (long)blockIdx.y * 128;
    const int tm = tid >> 4, tn = tid & 15;
    const int lr = tid >> 2;
    const int lk = (tid & 3) * 4;
    float acc[8][8] = {};

    for (int k0 = 0; k0 < K; k0 += 16) {
        float4 a0 = *(const float4*)(A + (m0 + lr) * (long)lda + k0 + lk);
        float4 a1 = *(const float4*)(A + (m0 + lr + 64) * (long)lda + k0 + lk);
        As[lk + 0][lr] = a0.x; As[lk + 1][lr] = a0.y; As[lk + 2][lr] = a0.z; As[lk + 3][lr] = a0.w;
        As[lk + 0][lr + 64] = a1.x; As[lk + 1][lr + 64] = a1.y; As[lk + 2][lr + 64] = a1.z; As[lk + 3][lr + 64] = a1.w;
        if (BT) {
            float4 b0 = *(const float4*)(B + (n0 + lr) * (long)ldb + k0 + lk);
            float4 b1 = *(const float4*)(B + (n0 + lr + 64) * (long)ldb + k0 + lk);
            Bs[lk + 0][lr] = b0.x; Bs[lk + 1][lr] = b0.y; Bs[lk + 2][lr] = b0.z; Bs[lk + 3][lr] = b0.w;
            Bs[lk + 0][lr + 64] = b1.x; Bs[lk + 1][lr + 64] = b1.y; Bs[lk + 2][lr + 64] = b1.z; Bs[lk + 3][lr + 64] = b1.w;
        } else {
            const int r = tid >> 5;
            const int c4 = (tid & 31) * 4;
            *(float4*)&Bs[r][c4]     = *(const float4*)(B + (long)(k0 + r) * ldb + n0 + c4);
            *(float4*)&Bs[r + 8][c4] = *(const float4*)(B + (long)(k0 + r + 8) * ldb + n0 + c4);
        }
        __syncthreads();
        #pragma unroll
        for (int kk = 0; kk < 16; ++kk) {
            float a[8], b[8];
            *(float4*)&a[0] = *(const float4*)&As[kk][tm * 8];
            *(float4*)&a[4] = *(const float4*)&As[kk][tm * 8 + 4];
            *(float4*)&b[0] = *(const float4*)&Bs[kk][tn * 8];
            *(float4*)&b[4] = *(const float4*)&Bs[kk][tn * 8 + 4];
            #pragma unroll
            for (int i = 0; i < 8; ++i)
                #pragma unroll
                for (int j = 0; j < 8; ++j)
                    acc[i][j] = fmaf(a[i], b[j], acc[i][j]);
        }
        __syncthreads();
    }
    #pragma unroll
    for (int i = 0; i < 8; ++i) {
        float* crow = C + (m0 + tm * 8 + i) * (long)ldc + n0 + tn * 8;
        #pragma unroll
        for (int j = 0; j < 8; ++j) {
            float v = acc[i][j];
            if (BIAS)  v += bias[n0 + tn * 8 + j];
            if (ACCUM) v += crow[j];
            crow[j] = v;
        }
    }
}

// ---------------- fused 2-layer GRU wavefront (cooperative launch, monotone tree barrier) ----------------
// Blocks 0-63: layer A at step g. Blocks 64-127: layer B at step g-1 (consumes ysA[g-1]).
// ys published via agent-scope (sc1) write-through atomic stores; h/x staged via agent-scope
// atomic loads (MALL = single coherence point; no fences). __syncthreads() before arrival
// drains vmcnt (sc1 stores complete at MALL first).
__global__ __launch_bounds__(512)
void gru2_rec(const float* __restrict__ whhA, const float* __restrict__ bhhA,
              const float* __restrict__ giA,  const float* __restrict__ h0A,
              const float* __restrict__ wihB, const float* __restrict__ bihB,
              const float* __restrict__ whhB, const float* __restrict__ bhhB,
              const float* __restrict__ h0B,
              float* __restrict__ ysA, float* __restrict__ ysB, int T,
              unsigned* __restrict__ cnt)
{
    __shared__ float lds[2048];
    const int tid = threadIdx.x;
    const int wave = tid >> 6, lane = tid & 63;
    const int role = blockIdx.x >> 6;        // 0 = layer A, 1 = layer B
    const int rbid = blockIdx.x & 63;
    const int u0 = (rbid * 8 + wave) * 2;    // even unit index; this wave owns u0, u0+1
    const int c0 = lane * 16;
    bool dead = false;

    union { unsigned long long q; float f[2]; float2 v; } cv;

    if (role == 0) {
        // ---- layer A: recurrent matvec only ----
        float w[3][2][16];
        #pragma unroll
        for (int gt = 0; gt < 3; ++gt)
            #pragma unroll
            for (int k = 0; k < 2; ++k) {
                const float* p = whhA + (long)(u0 + k + gt * 1024) * HID + c0;
                #pragma unroll
                for (int j = 0; j < 16; j += 4) *(float4*)&w[gt][k][j] = *(const float4*)(p + j);
            }
        const float2 bR = *(const float2*)&bhhA[u0];
        const float2 bZ = *(const float2*)&bhhA[u0 + 1024];
        const float2 bN = *(const float2*)&bhhA[u0 + 2048];
        float2 gR = *(const float2*)&giA[u0];
        float2 gZ = *(const float2*)&giA[u0 + 1024];
        float2 gN = *(const float2*)&giA[u0 + 2048];

        for (int g = 0; g <= T; ++g) {
            if (g < T) {
                const float* hsrc = (g == 0) ? h0A : ysA + (long)(g - 1) * HID;
                cv.q = ld_mall((const unsigned long long*)hsrc + tid);
                lds[tid * 2] = cv.f[0]; lds[tid * 2 + 1] = cv.f[1];
                __syncthreads();
                float hv[16];
                #pragma unroll
                for (int j = 0; j < 16; j += 4) *(float4*)&hv[j] = *(const float4*)&lds[c0 + j];
                float a[3][2] = {};
                #pragma unroll
                for (int j = 0; j < 16; ++j)
                    #pragma unroll
                    for (int gt = 0; gt < 3; ++gt) {
                        a[gt][0] = fmaf(w[gt][0][j], hv[j], a[gt][0]);
                        a[gt][1] = fmaf(w[gt][1][j], hv[j], a[gt][1]);
                    }
                #pragma unroll
                for (int gt = 0; gt < 3; ++gt) {
                    a[gt][0] = wave_red(a[gt][0]);
                    a[gt][1] = wave_red(a[gt][1]);
                }
                if (lane == 0) {
                    float r0 = 1.f / (1.f + expf(-(gR.x + a[0][0] + bR.x)));
                    float z0 = 1.f / (1.f + expf(-(gZ.x + a[1][0] + bZ.x)));
                    float n0 = tanhf(gN.x + r0 * (a[2][0] + bN.x));
                    float r1 = 1.f / (1.f + expf(-(gR.y + a[0][1] + bR.y)));
                    float z1 = 1.f / (1.f + expf(-(gZ.y + a[1][1] + bZ.y)));
                    float n1 = tanhf(gN.y + r1 * (a[2][1] + bN.y));
                    union { unsigned long long q; float2 v; } outv;
                    outv.v.x = (1.f - z0) * n0 + z0 * lds[u0];
                    outv.v.y = (1.f - z1) * n1 + z1 * lds[u0 + 1];
                    st_mall(&ysA[(long)g * HID + u0], outv.q);
                }
                const long nb = (long)((g + 1 < T) ? g + 1 : g) * G3;
                gR = *(const float2*)&giA[nb + u0];
                gZ = *(const float2*)&giA[nb + u0 + 1024];
                gN = *(const float2*)&giA[nb + u0 + 2048];
            }
            __syncthreads();   // drains vmcnt: sc1 ys stores complete at MALL before arrival
            if (tid == 0) tree_barrier(cnt, g, blockIdx.x, dead);
            __syncthreads();
        }
    } else {
        // ---- layer B: input projection (from ysA) + recurrent matvec ----
        float wi[3][2][16], wh[3][2][16];
        #pragma unroll
        for (int gt = 0; gt < 3; ++gt)
            #pragma unroll
            for (int k = 0; k < 2; ++k) {
                const float* pI = wihB + (long)(u0 + k + gt * 1024) * HID + c0;
                const float* pH = whhB + (long)(u0 + k + gt * 1024) * HID + c0;
                #pragma unroll
                for (int j = 0; j < 16; j += 4) {
                    *(float4*)&wi[gt][k][j] = *(const float4*)(pI + j);
                    *(float4*)&wh[gt][k][j] = *(const float4*)(pH + j);
                }
            }
        const float2 biR = *(const float2*)&bihB[u0];
        const float2 biZ = *(const float2*)&bihB[u0 + 1024];
        const float2 biN = *(const float2*)&bihB[u0 + 2048];
        const float2 bhR = *(const float2*)&bhhB[u0];
        const float2 bhZ = *(const float2*)&bhhB[u0 + 1024];
        const float2 bhN = *(const float2*)&bhhB[u0 + 2048];

        for (int g = 0; g <= T; ++g) {
            const int s = g - 1;
            if (s >= 0) {
                const float* xsrc = ysA + (long)s * HID;
                const float* hsrc = (s == 0) ? h0B : ysB + (long)(s - 1) * HID;
                cv.q = ld_mall((const unsigned long long*)xsrc + tid);
                lds[tid * 2] = cv.f[0]; lds[tid * 2 + 1] = cv.f[1];
                cv.q = ld_mall((const unsigned long long*)hsrc + tid);
                lds[1024 + tid * 2] = cv.f[0]; lds[1024 + tid * 2 + 1] = cv.f[1];
                __syncthreads();
                float xv[16], hv[16];
                #pragma unroll
                for (int j = 0; j < 16; j += 4) {
                    *(float4*)&xv[j] = *(const float4*)&lds[c0 + j];
                    *(float4*)&hv[j] = *(const float4*)&lds[1024 + c0 + j];
                }
                float a_r[2] = {}, a_z[2] = {}, a_ni[2] = {}, a_nh[2] = {};
                #pragma unroll
                for (int j = 0; j < 16; ++j)
                    #pragma unroll
                    for (int k = 0; k < 2; ++k) {
                        a_r[k]  = fmaf(wi[0][k][j], xv[j], a_r[k]);
                        a_r[k]  = fmaf(wh[0][k][j], hv[j], a_r[k]);
                        a_z[k]  = fmaf(wi[1][k][j], xv[j], a_z[k]);
                        a_z[k]  = fmaf(wh[1][k][j], hv[j], a_z[k]);
                        a_ni[k] = fmaf(wi[2][k][j], xv[j], a_ni[k]);
                        a_nh[k] = fmaf(wh[2][k][j], hv[j], a_nh[k]);
                    }
                #pragma unroll
                for (int k = 0; k < 2; ++k) {
                    a_r[k]  = wave_red(a_r[k]);
                    a_z[k]  = wave_red(a_z[k]);
                    a_ni[k] = wave_red(a_ni[k]);
                    a_nh[k] = wave_red(a_nh[k]);
                }
                if (lane == 0) {
                    float r0 = 1.f / (1.f + expf(-(a_r[0] + biR.x + bhR.x)));
                    float z0 = 1.f / (1.f + expf(-(a_z[0] + biZ.x + bhZ.x)));
                    float n0 = tanhf(a_ni[0] + biN.x + r0 * (a_nh[0] + bhN.x));
                    float r1 = 1.f / (1.f + expf(-(a_r[1] + biR.y + bhR.y)));
                    float z1 = 1.f / (1.f + expf(-(a_z[1] + biZ.y + bhZ.y)));
                    float n1 = tanhf(a_ni[1] + biN.y + r1 * (a_nh[1] + bhN.y));
                    union { unsigned long long q; float2 v; } outv;
                    outv.v.x = (1.f - z0) * n0 + z0 * lds[1024 + u0];
                    outv.v.y = (1.f - z1) * n1 + z1 * lds[1024 + u0 + 1];
                    st_mall(&ysB[(long)s * HID + u0], outv.q);
                }
            }
            __syncthreads();   // drains vmcnt before arrival
            if (tid == 0) tree_barrier(cnt, g, blockIdx.x, dead);
            __syncthreads();
        }
    }
}

// ---------------- row softmax (2048 rows x 4096 cols, in place) ----------------
__global__ __launch_bounds__(256) void softmax_rows(float* __restrict__ S)
{
    __shared__ float red[8];
    float* p = S + blockIdx.x * 4096L;
    const int t = threadIdx.x;
    const int wave = t >> 6, lane = t & 63;
    float4 v[4];
    float mx = -3.4e38f;
    #pragma unroll
    for (int j = 0; j < 4; ++j) {
        v[j] = *(float4*)(p + (j * 256 + t) * 4);
        mx = fmaxf(mx, fmaxf(fmaxf(v[j].x, v[j].y), fmaxf(v[j].z, v[j].w)));
    }
    #pragma unroll
    for (int o = 32; o; o >>= 1) mx = fmaxf(mx, __shfl_xor(mx, o));
    if (lane == 0) red[wave] = mx;
    __syncthreads();
    mx = fmaxf(fmaxf(red[0], red[1]), fmaxf(red[2], red[3]));
    float sm = 0.f;
    #pragma unroll
    for (int j = 0; j < 4; ++j) {
        v[j].x = expf(v[j].x - mx); v[j].y = expf(v[j].y - mx);
        v[j].z = expf(v[j].z - mx); v[j].w = expf(v[j].w - mx);
        sm += v[j].x + v[j].y + v[j].z + v[j].w;
    }
    #pragma unroll
    for (int o = 32; o; o >>= 1) sm += __shfl_xor(sm, o);
    if (lane == 0) red[4 + wave] = sm;
    __syncthreads();
    sm = red[4] + red[5] + red[6] + red[7];
    const float inv = 1.f / sm;
    #pragma unroll
    for (int j = 0; j < 4; ++j) {
        v[j].x *= inv; v[j].y *= inv; v[j].z *= inv; v[j].w *= inv;
        *(float4*)(p + (j * 256 + t) * 4) = v[j];
    }
}

extern "C" void kernel_launch(void* const* d_in, const int* in_sizes, int n_in,
                              void* d_out, int out_size, void* d_ws, size_t ws_size,
                              hipStream_t stream)
{
    const int*   inputs  = (const int*)d_in[0];
    const int*   targets = (const int*)d_in[1];
    const float* emb     = (const float*)d_in[2];
    const float* ewih0   = (const float*)d_in[3];
    const float* ewhh0   = (const float*)d_in[4];
    const float* ebih0   = (const float*)d_in[5];
    const float* ebhh0   = (const float*)d_in[6];
    const float* ewih1   = (const float*)d_in[7];
    const float* ewhh1   = (const float*)d_in[8];
    const float* ebih1   = (const float*)d_in[9];
    const float* ebhh1   = (const float*)d_in[10];
    const float* dwih0   = (const float*)d_in[11];
    const float* dwhh0   = (const float*)d_in[12];
    const float* dbih0   = (const float*)d_in[13];
    const float* dbhh0   = (const float*)d_in[14];
    const float* dwih1   = (const float*)d_in[15];
    const float* dwhh1   = (const float*)d_in[16];
    const float* dbih1   = (const float*)d_in[17];
    const float* dbhh1   = (const float*)d_in[18];
    const float* proj_w  = (const float*)d_in[19];
    const float* proj_b  = (const float*)d_in[20];
    float* out = (float*)d_out;

    char* ws = (char*)d_ws;
    if (ws_size < WS_NEED) return;

    float* Gi   = (float*)(ws + GI_OFF);
    float* Smat = (float*)(ws + S_OFF);
    float* Ctx  = (float*)(ws + CTX_OFF);
    float* X0   = (float*)(ws + X0_OFF);
    float* Dem  = (float*)(ws + DEM_OFF);
    float* Hl0  = (float*)(ws + HL0_OFF);
    float* ys0  = (float*)(ws + YS0_OFF);
    float* Hl1  = (float*)(ws + HL1_OFF);
    float* Enc  = (float*)(ws + ENC_OFF);
    unsigned* bar = (unsigned*)(ws + BAR_OFF);
    float* h0z  = (float*)(ws + H0_OFF);

    // zero barrier counters + initial hidden state (re-runs on every graph replay)
    hipMemsetAsync(ws + BAR_OFF, 0, 8192, stream);

    auto launch_rec2 = [&](const float* whhA, const float* bhhA, const float* giA, const float* h0A,
                           const float* wihB, const float* bihB, const float* whhB, const float* bhhB,
                           const float* h0B, float* ysA, float* ysB, int T, unsigned* cntp) {
        void* args[] = {(void*)&whhA, (void*)&bhhA, (void*)&giA, (void*)&h0A,
                        (void*)&wihB, (void*)&bihB, (void*)&whhB, (void*)&bhhB,
                        (void*)&h0B, (void*)&ysA, (void*)&ysB, (void*)&T, (void*)&cntp};
        hipLaunchCooperativeKernel((const void*)gru2_rec, dim3(NWG), dim3(512), args, 0, stream);
    };

    // ---- encoder: gather + l0 gate-input GEMM, then fused l0+l1 wavefront ----
    gather_emb<<<SENC, 256, 0, stream>>>(emb, inputs, X0, 86, 0);
    gemm_f32<true, false, true><<<dim3(32, 24), 256, 0, stream>>>(X0, HID, ewih0, HID, Gi, G3, HID, ebih0);
    gather_emb<<<TDEC, 256, 0, stream>>>(emb, targets, Dem, 86, 1);
    launch_rec2(ewhh0, ebhh0, Gi, h0z,
                ewih1, ebih1, ewhh1, ebhh1, h0z,
                ys0, Enc, SENC, bar + 0);

    // ---- decoder: l0 gate-input GEMM, then fused l0+l1 wavefront ----
    gemm_f32<true, false, true><<<dim3(16, 24), 256, 0, stream>>>(Dem, HID, dwih0, HID, Gi, G3, HID, dbih0);
    launch_rec2(dwhh0, dbhh0, Gi, ys0 + 4095L * HID,
                dwih1, dbih1, dwhh1, dbhh1, Enc + 4095L * HID,
                Hl0, Hl1, TDEC, bar + 256);

    // ---- attention + projection (all batched) ----
    gemm_f32<true, false, false><<<dim3(16, 32), 256, 0, stream>>>(Hl1, HID, Enc, HID, Smat, SENC, HID, nullptr);
    softmax_rows<<<TDEC, 256, 0, stream>>>(Smat);
    gemm_f32<false, false, false><<<dim3(16, 8), 256, 0, stream>>>(Smat, SENC, Enc, HID, Ctx, HID, SENC, nullptr);
    gemm_f32<true, false, true><<<dim3(16, 2), 256, 0, stream>>>(Hl1, HID, proj_w, 2 * HID, out, 256, HID, proj_b);
    gemm_f32<true, true, false><<<dim3(16, 2), 256, 0, stream>>>(Ctx, HID, proj_w + HID, 2 * HID, out, 256, HID, nullptr);
}